// Round 10
// baseline (357.798 us; speedup 1.0000x reference)
//
#include <hip/hip_runtime.h>

// GCN 3-layer forward: N=100000 nodes, E=1600000 edges, D=64.
// Bucketed CSR build (round 7) + gather-only aggregation (round 5).
// Round 10: GEMM fix — wave-per-row/lane-per-col kept, but A row read via
// 16 INDEPENDENT per-lane float4 broadcast loads (vector path, real MLP)
// instead of 4 serial scalar s_loads, and 4 accumulator chains instead of
// one 64-deep chain. Round-9 failure was scalar-load latency with zero MLP
// (SGPR=112 proved scalarization; VALUBusy 17%, 83% stall).

#define THREADS 256
#define NPB_SHIFT 9
#define NPB 512            // nodes per bucket (power of 2)
#define STAGE_CAP 9216     // >= mean 8163 + 11 sigma; LDS stage capacity

// ---- pass A: bucket histogram (LDS-aggregated) ---------------------------
__global__ __launch_bounds__(THREADS) void k_bhist(
    const int* __restrict__ dst, int* __restrict__ bucketCnt, int E) {
  __shared__ int hist[256];
  int t = threadIdx.x;
  hist[t] = 0;
  __syncthreads();
  int blockStart = blockIdx.x * 4096;
#pragma unroll
  for (int c = 0; c < 4; c++) {
    int e0 = blockStart + c * 1024 + t * 4;
    if (e0 + 3 < E) {
      int4 d = *(const int4*)(dst + e0);
      atomicAdd(&hist[d.x >> NPB_SHIFT], 1);
      atomicAdd(&hist[d.y >> NPB_SHIFT], 1);
      atomicAdd(&hist[d.z >> NPB_SHIFT], 1);
      atomicAdd(&hist[d.w >> NPB_SHIFT], 1);
    } else {
      int lim = min(e0 + 4, E);
      for (int e = e0; e < lim; e++) atomicAdd(&hist[dst[e] >> NPB_SHIFT], 1);
    }
  }
  __syncthreads();
  if (hist[t]) atomicAdd(&bucketCnt[t], hist[t]);
}

// ---- pass B: scan bucket counts (single block) ---------------------------
__global__ __launch_bounds__(THREADS) void k_bscan(
    const int* __restrict__ bucketCnt, int* __restrict__ bucketOff,
    int* __restrict__ bucketCur, int* __restrict__ rowptr,
    int n, int E, int nbuck) {
  __shared__ int sh[THREADS];
  int t = threadIdx.x;
  int v = (t < nbuck) ? bucketCnt[t] : 0;
  sh[t] = v;
  __syncthreads();
  for (int off = 1; off < THREADS; off <<= 1) {
    int u = (t >= off) ? sh[t - off] : 0;
    __syncthreads();
    sh[t] += u;
    __syncthreads();
  }
  if (t < nbuck) {
    int ex = sh[t] - v;
    bucketOff[t] = ex;
    bucketCur[t] = ex;
  }
  if (t == 0) {
    bucketOff[nbuck] = E;
    rowptr[n] = E;
  }
}

// ---- pass C: bin edges into bucket runs (packed (ln<<17)|src) ------------
__global__ __launch_bounds__(THREADS) void k_bscat(
    const int* __restrict__ src, const int* __restrict__ dst,
    int* __restrict__ bucketCur, int* __restrict__ eb, int E) {
  __shared__ int hcur[256];
  int t = threadIdx.x;
  hcur[t] = 0;
  __syncthreads();
  int blockStart = blockIdx.x * 4096;
  // count
#pragma unroll
  for (int c = 0; c < 4; c++) {
    int e0 = blockStart + c * 1024 + t * 4;
    if (e0 + 3 < E) {
      int4 d = *(const int4*)(dst + e0);
      atomicAdd(&hcur[d.x >> NPB_SHIFT], 1);
      atomicAdd(&hcur[d.y >> NPB_SHIFT], 1);
      atomicAdd(&hcur[d.z >> NPB_SHIFT], 1);
      atomicAdd(&hcur[d.w >> NPB_SHIFT], 1);
    } else {
      int lim = min(e0 + 4, E);
      for (int e = e0; e < lim; e++) atomicAdd(&hcur[dst[e] >> NPB_SHIFT], 1);
    }
  }
  __syncthreads();
  // reserve a contiguous run per (block, bucket)
  int c0 = hcur[t];
  int rb = 0;
  if (c0) rb = atomicAdd(&bucketCur[t], c0);
  __syncthreads();
  hcur[t] = rb;
  __syncthreads();
  // place
#pragma unroll
  for (int c = 0; c < 4; c++) {
    int e0 = blockStart + c * 1024 + t * 4;
    if (e0 + 3 < E) {
      int4 s = *(const int4*)(src + e0);
      int4 d = *(const int4*)(dst + e0);
      int q;
      q = atomicAdd(&hcur[d.x >> NPB_SHIFT], 1); eb[q] = ((d.x & (NPB - 1)) << 17) | s.x;
      q = atomicAdd(&hcur[d.y >> NPB_SHIFT], 1); eb[q] = ((d.y & (NPB - 1)) << 17) | s.y;
      q = atomicAdd(&hcur[d.z >> NPB_SHIFT], 1); eb[q] = ((d.z & (NPB - 1)) << 17) | s.z;
      q = atomicAdd(&hcur[d.w >> NPB_SHIFT], 1); eb[q] = ((d.w & (NPB - 1)) << 17) | s.w;
    } else {
      int lim = min(e0 + 4, E);
      for (int e = e0; e < lim; e++) {
        int dd = dst[e];
        int q = atomicAdd(&hcur[dd >> NPB_SHIFT], 1);
        eb[q] = ((dd & (NPB - 1)) << 17) | src[e];
      }
    }
  }
}

// ---- pass D: per-bucket CSR finalize (all-coalesced global writes) -------
__global__ __launch_bounds__(THREADS) void k_bcsr(
    const int* __restrict__ eb, const int* __restrict__ bucketOff,
    int* __restrict__ rowptr, float* __restrict__ dinv,
    int* __restrict__ es, int n) {
  __shared__ int lcnt[NPB];
  __shared__ int sA[NPB];
  __shared__ int sB[NPB];
  __shared__ int lcur[NPB];
  __shared__ int stage[STAGE_CAP];
  int b = blockIdx.x;
  int t = threadIdx.x;
  int base = bucketOff[b], end = bucketOff[b + 1];
  int cntB = end - base;
  int node0 = b << NPB_SHIFT;
  int nn = min(NPB, n - node0);

  lcnt[t] = 0; lcnt[t + 256] = 0;
  __syncthreads();
  for (int p = t; p < cntB; p += THREADS) {
    int v = eb[base + p];
    atomicAdd(&lcnt[v >> 17], 1);
  }
  __syncthreads();
  sA[t] = lcnt[t]; sA[t + 256] = lcnt[t + 256];
  __syncthreads();
  int* bin = sA; int* bout = sB;
  for (int off = 1; off < NPB; off <<= 1) {
    int j0 = t, j1 = t + 256;
    int a0 = bin[j0] + ((j0 >= off) ? bin[j0 - off] : 0);
    int a1 = bin[j1] + ((j1 >= off) ? bin[j1 - off] : 0);
    bout[j0] = a0; bout[j1] = a1;
    __syncthreads();
    int* tmp = bin; bin = bout; bout = tmp;
  }
#pragma unroll
  for (int k = 0; k < 2; k++) {
    int j = t + k * 256;
    if (j < nn) {
      int c = lcnt[j];
      int ex = bin[j] - c;
      rowptr[node0 + j] = base + ex;
      dinv[node0 + j] = rsqrtf((float)c + 1.f);
      lcur[j] = ex;
    }
  }
  __syncthreads();
  for (int p = t; p < cntB; p += THREADS) {
    int v = eb[base + p];
    int q = atomicAdd(&lcur[v >> 17], 1);
    if (q < STAGE_CAP) stage[q] = v & 0x1FFFF;
  }
  __syncthreads();
  int lim = min(cntB, STAGE_CAP);
  for (int q = t; q < lim; q += THREADS) es[base + q] = stage[q];
}

// ---- dense GEMM + row scale: C[r,:] = (A[r,:] @ W) * dinv[r] -------------
// Wave per row (grid-stride), lane per column. W column in 64 VGPRs/lane.
// A row via 16 independent per-lane float4 broadcast loads (coalesced to
// one 16B request each); 4 accumulator chains.
__global__ __launch_bounds__(THREADS) void k_gemmW(
    const float* __restrict__ A, const float* __restrict__ W,
    const float* __restrict__ dinv, float* __restrict__ C, int n) {
  int lane = threadIdx.x & 63;
  int wv = (int)((blockIdx.x * blockDim.x + threadIdx.x) >> 6);  // divergent-typed
  int nw = (gridDim.x * blockDim.x) >> 6;

  // W column 'lane' -> registers (coalesced 256B per load, once per wave)
  float w[64];
#pragma unroll
  for (int k = 0; k < 64; k++) w[k] = W[k * 64 + lane];

  for (int r = wv; r < n; r += nw) {
    const float4* __restrict__ A4 = (const float4*)(A + (size_t)r * 64);
    float acc0 = 0.f, acc1 = 0.f, acc2 = 0.f, acc3 = 0.f;
#pragma unroll
    for (int c = 0; c < 4; c++) {
      float4 a0 = A4[c * 4 + 0];
      float4 a1 = A4[c * 4 + 1];
      float4 a2 = A4[c * 4 + 2];
      float4 a3 = A4[c * 4 + 3];
      int k0 = c * 16;
      acc0 = fmaf(a0.x, w[k0 + 0],  acc0);
      acc1 = fmaf(a0.y, w[k0 + 1],  acc1);
      acc2 = fmaf(a0.z, w[k0 + 2],  acc2);
      acc3 = fmaf(a0.w, w[k0 + 3],  acc3);
      acc0 = fmaf(a1.x, w[k0 + 4],  acc0);
      acc1 = fmaf(a1.y, w[k0 + 5],  acc1);
      acc2 = fmaf(a1.z, w[k0 + 6],  acc2);
      acc3 = fmaf(a1.w, w[k0 + 7],  acc3);
      acc0 = fmaf(a2.x, w[k0 + 8],  acc0);
      acc1 = fmaf(a2.y, w[k0 + 9],  acc1);
      acc2 = fmaf(a2.z, w[k0 + 10], acc2);
      acc3 = fmaf(a2.w, w[k0 + 11], acc3);
      acc0 = fmaf(a3.x, w[k0 + 12], acc0);
      acc1 = fmaf(a3.y, w[k0 + 13], acc1);
      acc2 = fmaf(a3.z, w[k0 + 14], acc2);
      acc3 = fmaf(a3.w, w[k0 + 15], acc3);
    }
    C[(size_t)r * 64 + lane] = ((acc0 + acc1) + (acc2 + acc3)) * dinv[r];
  }
}

// ---- gather aggregation: wave per node, 4 edges x float4 lanes -----------
// hs = row-scaled features (hs[r] = h[r]*dinv[r]).
// out[i][:] = relu( dinv[i] * (sum_edges hs[src] + hs[i]) + b )
template <int RELU>
__global__ __launch_bounds__(THREADS) void k_agg64(
    const float* __restrict__ hs, const float* __restrict__ dinv,
    const int* __restrict__ rowptr, const int* __restrict__ es,
    const float* __restrict__ b, float* __restrict__ out, int n) {
  int i = (blockIdx.x * THREADS + threadIdx.x) >> 6;
  if (i >= n) return;
  int lane = threadIdx.x & 63;
  int g = lane >> 4;        // edge slot 0..3
  int c = lane & 15;        // float4 column group
  const float4* h4 = (const float4*)hs;
  int p1 = rowptr[i + 1];
  int p = rowptr[i] + g;
  float4 acc  = make_float4(0.f, 0.f, 0.f, 0.f);
  float4 acc2 = make_float4(0.f, 0.f, 0.f, 0.f);
  for (; p + 4 < p1; p += 8) {
    int s0 = es[p];
    int s1 = es[p + 4];
    float4 a0 = h4[(size_t)s0 * 16 + c];
    float4 a1 = h4[(size_t)s1 * 16 + c];
    acc.x  += a0.x; acc.y  += a0.y; acc.z  += a0.z; acc.w  += a0.w;
    acc2.x += a1.x; acc2.y += a1.y; acc2.z += a1.z; acc2.w += a1.w;
  }
  if (p < p1) {
    int s0 = es[p];
    float4 a0 = h4[(size_t)s0 * 16 + c];
    acc.x += a0.x; acc.y += a0.y; acc.z += a0.z; acc.w += a0.w;
  }
  acc.x += acc2.x; acc.y += acc2.y; acc.z += acc2.z; acc.w += acc2.w;
#pragma unroll
  for (int m = 16; m <= 32; m <<= 1) {
    acc.x += __shfl_xor(acc.x, m, 64);
    acc.y += __shfl_xor(acc.y, m, 64);
    acc.z += __shfl_xor(acc.z, m, 64);
    acc.w += __shfl_xor(acc.w, m, 64);
  }
  if (g == 0) {
    float di = dinv[i];
    float4 self = h4[(size_t)i * 16 + c];
    float4 bb = ((const float4*)b)[c];
    float4 r;
    r.x = di * (acc.x + self.x) + bb.x;
    r.y = di * (acc.y + self.y) + bb.y;
    r.z = di * (acc.z + self.z) + bb.z;
    r.w = di * (acc.w + self.w) + bb.w;
    if (RELU) {
      r.x = fmaxf(r.x, 0.f); r.y = fmaxf(r.y, 0.f);
      r.z = fmaxf(r.z, 0.f); r.w = fmaxf(r.w, 0.f);
    }
    ((float4*)out)[(size_t)i * 16 + c] = r;
  }
}

// ---- layer 3: g3[i] = (a2[i,:] @ W3) * dinv[i] ---------------------------
__global__ __launch_bounds__(THREADS) void k_gemv(
    const float* __restrict__ a2, const float* __restrict__ W3,
    const float* __restrict__ dinv, float* __restrict__ g3, int n) {
  int t = blockIdx.x * blockDim.x + threadIdx.x;
  int i = t >> 4, p = t & 15;
  if (i >= n) return;
  float4 v = ((const float4*)a2)[t];
  float4 w = ((const float4*)W3)[p];
  float sum = v.x * w.x + v.y * w.y + v.z * w.z + v.w * w.w;
  sum += __shfl_down(sum, 8, 16);
  sum += __shfl_down(sum, 4, 16);
  sum += __shfl_down(sum, 2, 16);
  sum += __shfl_down(sum, 1, 16);
  if (p == 0) g3[i] = sum * dinv[i];
}

// ---- layer-3 aggregation: thread per node --------------------------------
__global__ __launch_bounds__(THREADS) void k_agg1(
    const float* __restrict__ g3, const float* __restrict__ dinv,
    const int* __restrict__ rowptr, const int* __restrict__ es,
    const float* __restrict__ b3, float* __restrict__ out, int n) {
  int i = blockIdx.x * blockDim.x + threadIdx.x;
  if (i >= n) return;
  int p = rowptr[i], p1 = rowptr[i + 1];
  float acc = 0.f, accb = 0.f;
  for (; p + 1 < p1; p += 2) {
    acc  += g3[es[p]];
    accb += g3[es[p + 1]];
  }
  if (p < p1) acc += g3[es[p]];
  out[i] = dinv[i] * (acc + accb + g3[i]) + b3[0];
}

extern "C" void kernel_launch(void* const* d_in, const int* in_sizes, int n_in,
                              void* d_out, int out_size, void* d_ws, size_t ws_size,
                              hipStream_t stream) {
  const float* x  = (const float*)d_in[0];
  const int*   ei = (const int*)d_in[1];
  const float* W1 = (const float*)d_in[2];
  const float* b1 = (const float*)d_in[3];
  const float* W2 = (const float*)d_in[4];
  const float* b2 = (const float*)d_in[5];
  const float* W3 = (const float*)d_in[6];
  const float* b3 = (const float*)d_in[7];
  float* out = (float*)d_out;

  const int n = in_sizes[0] / 64;    // 100000
  const int E = in_sizes[1] / 2;     // 1600000
  const int* src = ei;
  const int* dst = ei + E;
  const int nbuck = (n + NPB - 1) >> NPB_SHIFT;       // 196
  const int nA = (E + 4095) / 4096;                   // blocks for hist/scat

  // workspace layout, 256B-aligned regions
  char* w = (char*)d_ws;
  auto alloc = [&](size_t bytes) -> void* {
    void* p = (void*)w;
    w += (bytes + 255) & ~(size_t)255;
    return p;
  };
  int*   bucketCnt = (int*)alloc(256 * 4);
  int*   bucketOff = (int*)alloc(257 * 4);
  int*   bucketCur = (int*)alloc(256 * 4);
  int*   rowptr    = (int*)alloc(((size_t)n + 1) * 4);
  int*   eb        = (int*)alloc((size_t)E * 4);
  int*   es        = (int*)alloc((size_t)E * 4);
  float* dinv      = (float*)alloc((size_t)n * 4);
  float* g3        = (float*)alloc((size_t)n * 4);
  float* bufA      = (float*)alloc((size_t)n * 64 * 4);
  float* bufB      = (float*)alloc((size_t)n * 64 * 4);

  const int gN    = (n + THREADS - 1) / THREADS;
  const int gN16  = ((n * 16) + THREADS - 1) / THREADS;
  const int gGemm = 1024;              // 4096 waves, ~24 rows each
  const int gWave = (n + 3) / 4;

  // bucketed CSR build
  hipMemsetAsync(bucketCnt, 0, 256 * 4, stream);
  k_bhist<<<nA, THREADS, 0, stream>>>(dst, bucketCnt, E);
  k_bscan<<<1, THREADS, 0, stream>>>(bucketCnt, bucketOff, bucketCur, rowptr, n, E, nbuck);
  k_bscat<<<nA, THREADS, 0, stream>>>(src, dst, bucketCur, eb, E);
  k_bcsr<<<nbuck, THREADS, 0, stream>>>(eb, bucketOff, rowptr, dinv, es, n);

  // layer 1: hs1 = (x@W1)*dinv -> bufA; a1 = agg(hs1) -> bufB
  k_gemmW<<<gGemm, THREADS, 0, stream>>>(x, W1, dinv, bufA, n);
  k_agg64<1><<<gWave, THREADS, 0, stream>>>(bufA, dinv, rowptr, es, b1, bufB, n);
  // layer 2: hs2 = (a1@W2)*dinv -> bufA; a2 = agg(hs2) -> bufB
  k_gemmW<<<gGemm, THREADS, 0, stream>>>(bufB, W2, dinv, bufA, n);
  k_agg64<1><<<gWave, THREADS, 0, stream>>>(bufA, dinv, rowptr, es, b2, bufB, n);
  // layer 3: g3 = (a2@W3)*dinv; out = dinv*(agg(g3)+g3) + b3
  k_gemv<<<gN16, THREADS, 0, stream>>>(bufB, W3, dinv, g3, n);
  k_agg1<<<gN, THREADS, 0, stream>>>(g3, dinv, rowptr, es, b3, out, n);
}

// Round 11
// 246.843 us; speedup vs baseline: 1.4495x; 1.4495x over previous
//
#include <hip/hip_runtime.h>

// GCN 3-layer forward: N=100000 nodes, E=1600000 edges, D=64.
// Bucketed CSR build (round 7) + gather-only aggregation (round 5).
// Round 11: GEMM via LDS-broadcast — A tile staged with coalesced
// distinct-address loads, rows read back as same-address ds_read_b128
// (LDS broadcasts are free); W column in 64 VGPRs/lane. Rounds 7-10
// bracketed the failure modes: LDS-instr-bound, VGPR-blown, scalar-serial,
// uniform-address VMEM. This uses the only two fast paths: coalesced
// distinct-address global + same-address LDS broadcast.

#define THREADS 256
#define NPB_SHIFT 9
#define NPB 512            // nodes per bucket (power of 2)
#define STAGE_CAP 9216     // >= mean 8163 + 11 sigma; LDS stage capacity

// ---- pass A: bucket histogram (LDS-aggregated) ---------------------------
__global__ __launch_bounds__(THREADS) void k_bhist(
    const int* __restrict__ dst, int* __restrict__ bucketCnt, int E) {
  __shared__ int hist[256];
  int t = threadIdx.x;
  hist[t] = 0;
  __syncthreads();
  int blockStart = blockIdx.x * 4096;
#pragma unroll
  for (int c = 0; c < 4; c++) {
    int e0 = blockStart + c * 1024 + t * 4;
    if (e0 + 3 < E) {
      int4 d = *(const int4*)(dst + e0);
      atomicAdd(&hist[d.x >> NPB_SHIFT], 1);
      atomicAdd(&hist[d.y >> NPB_SHIFT], 1);
      atomicAdd(&hist[d.z >> NPB_SHIFT], 1);
      atomicAdd(&hist[d.w >> NPB_SHIFT], 1);
    } else {
      int lim = min(e0 + 4, E);
      for (int e = e0; e < lim; e++) atomicAdd(&hist[dst[e] >> NPB_SHIFT], 1);
    }
  }
  __syncthreads();
  if (hist[t]) atomicAdd(&bucketCnt[t], hist[t]);
}

// ---- pass B: scan bucket counts (single block) ---------------------------
__global__ __launch_bounds__(THREADS) void k_bscan(
    const int* __restrict__ bucketCnt, int* __restrict__ bucketOff,
    int* __restrict__ bucketCur, int* __restrict__ rowptr,
    int n, int E, int nbuck) {
  __shared__ int sh[THREADS];
  int t = threadIdx.x;
  int v = (t < nbuck) ? bucketCnt[t] : 0;
  sh[t] = v;
  __syncthreads();
  for (int off = 1; off < THREADS; off <<= 1) {
    int u = (t >= off) ? sh[t - off] : 0;
    __syncthreads();
    sh[t] += u;
    __syncthreads();
  }
  if (t < nbuck) {
    int ex = sh[t] - v;
    bucketOff[t] = ex;
    bucketCur[t] = ex;
  }
  if (t == 0) {
    bucketOff[nbuck] = E;
    rowptr[n] = E;
  }
}

// ---- pass C: bin edges into bucket runs (packed (ln<<17)|src) ------------
__global__ __launch_bounds__(THREADS) void k_bscat(
    const int* __restrict__ src, const int* __restrict__ dst,
    int* __restrict__ bucketCur, int* __restrict__ eb, int E) {
  __shared__ int hcur[256];
  int t = threadIdx.x;
  hcur[t] = 0;
  __syncthreads();
  int blockStart = blockIdx.x * 4096;
  // count
#pragma unroll
  for (int c = 0; c < 4; c++) {
    int e0 = blockStart + c * 1024 + t * 4;
    if (e0 + 3 < E) {
      int4 d = *(const int4*)(dst + e0);
      atomicAdd(&hcur[d.x >> NPB_SHIFT], 1);
      atomicAdd(&hcur[d.y >> NPB_SHIFT], 1);
      atomicAdd(&hcur[d.z >> NPB_SHIFT], 1);
      atomicAdd(&hcur[d.w >> NPB_SHIFT], 1);
    } else {
      int lim = min(e0 + 4, E);
      for (int e = e0; e < lim; e++) atomicAdd(&hcur[dst[e] >> NPB_SHIFT], 1);
    }
  }
  __syncthreads();
  // reserve a contiguous run per (block, bucket)
  int c0 = hcur[t];
  int rb = 0;
  if (c0) rb = atomicAdd(&bucketCur[t], c0);
  __syncthreads();
  hcur[t] = rb;
  __syncthreads();
  // place
#pragma unroll
  for (int c = 0; c < 4; c++) {
    int e0 = blockStart + c * 1024 + t * 4;
    if (e0 + 3 < E) {
      int4 s = *(const int4*)(src + e0);
      int4 d = *(const int4*)(dst + e0);
      int q;
      q = atomicAdd(&hcur[d.x >> NPB_SHIFT], 1); eb[q] = ((d.x & (NPB - 1)) << 17) | s.x;
      q = atomicAdd(&hcur[d.y >> NPB_SHIFT], 1); eb[q] = ((d.y & (NPB - 1)) << 17) | s.y;
      q = atomicAdd(&hcur[d.z >> NPB_SHIFT], 1); eb[q] = ((d.z & (NPB - 1)) << 17) | s.z;
      q = atomicAdd(&hcur[d.w >> NPB_SHIFT], 1); eb[q] = ((d.w & (NPB - 1)) << 17) | s.w;
    } else {
      int lim = min(e0 + 4, E);
      for (int e = e0; e < lim; e++) {
        int dd = dst[e];
        int q = atomicAdd(&hcur[dd >> NPB_SHIFT], 1);
        eb[q] = ((dd & (NPB - 1)) << 17) | src[e];
      }
    }
  }
}

// ---- pass D: per-bucket CSR finalize (all-coalesced global writes) -------
__global__ __launch_bounds__(THREADS) void k_bcsr(
    const int* __restrict__ eb, const int* __restrict__ bucketOff,
    int* __restrict__ rowptr, float* __restrict__ dinv,
    int* __restrict__ es, int n) {
  __shared__ int lcnt[NPB];
  __shared__ int sA[NPB];
  __shared__ int sB[NPB];
  __shared__ int lcur[NPB];
  __shared__ int stage[STAGE_CAP];
  int b = blockIdx.x;
  int t = threadIdx.x;
  int base = bucketOff[b], end = bucketOff[b + 1];
  int cntB = end - base;
  int node0 = b << NPB_SHIFT;
  int nn = min(NPB, n - node0);

  lcnt[t] = 0; lcnt[t + 256] = 0;
  __syncthreads();
  for (int p = t; p < cntB; p += THREADS) {
    int v = eb[base + p];
    atomicAdd(&lcnt[v >> 17], 1);
  }
  __syncthreads();
  sA[t] = lcnt[t]; sA[t + 256] = lcnt[t + 256];
  __syncthreads();
  int* bin = sA; int* bout = sB;
  for (int off = 1; off < NPB; off <<= 1) {
    int j0 = t, j1 = t + 256;
    int a0 = bin[j0] + ((j0 >= off) ? bin[j0 - off] : 0);
    int a1 = bin[j1] + ((j1 >= off) ? bin[j1 - off] : 0);
    bout[j0] = a0; bout[j1] = a1;
    __syncthreads();
    int* tmp = bin; bin = bout; bout = tmp;
  }
#pragma unroll
  for (int k = 0; k < 2; k++) {
    int j = t + k * 256;
    if (j < nn) {
      int c = lcnt[j];
      int ex = bin[j] - c;
      rowptr[node0 + j] = base + ex;
      dinv[node0 + j] = rsqrtf((float)c + 1.f);
      lcur[j] = ex;
    }
  }
  __syncthreads();
  for (int p = t; p < cntB; p += THREADS) {
    int v = eb[base + p];
    int q = atomicAdd(&lcur[v >> 17], 1);
    if (q < STAGE_CAP) stage[q] = v & 0x1FFFF;
  }
  __syncthreads();
  int lim = min(cntB, STAGE_CAP);
  for (int q = t; q < lim; q += THREADS) es[base + q] = stage[q];
}

// ---- dense GEMM + row scale: C[r,:] = (A[r,:] @ W) * dinv[r] -------------
// 16-row tiles, grid-stride. A tile staged into LDS with fully-coalesced
// distinct-address float4 loads; rows read back via same-address
// ds_read_b128 broadcasts (free). W column in 64 VGPRs per lane, loaded
// once per block. Wave w handles rows w*4..w*4+3; lane = output column.
__global__ __launch_bounds__(THREADS) void k_gemmT(
    const float* __restrict__ A, const float* __restrict__ W,
    const float* __restrict__ dinv, float* __restrict__ C, int n) {
  __shared__ float At[16 * 64];   // 4 KB
  int t = threadIdx.x;
  int lane = t & 63;
  int wid = t >> 6;               // wave 0..3

  // W column 'lane' -> 64 VGPRs (coalesced 256B per load, once per block)
  float w[64];
#pragma unroll
  for (int k = 0; k < 64; k++) w[k] = W[k * 64 + lane];

  int ntiles = (n + 15) >> 4;
  for (int tile = blockIdx.x; tile < ntiles; tile += gridDim.x) {
    int row0 = tile << 4;
    // stage: thread t loads float4 #t of the 16x64 tile (coalesced 4KB)
    {
      int r = row0 + (t >> 4);
      float4 v = make_float4(0.f, 0.f, 0.f, 0.f);
      if (r < n) v = ((const float4*)(A + (size_t)row0 * 64))[t];
      ((float4*)At)[t] = v;
    }
    __syncthreads();

#pragma unroll
    for (int j = 0; j < 4; j++) {
      int lr = wid * 4 + j;
      int r = row0 + lr;
      float acc0 = 0.f, acc1 = 0.f, acc2 = 0.f, acc3 = 0.f;
#pragma unroll
      for (int q = 0; q < 4; q++) {
        // same-address LDS reads -> broadcast, no conflict
        float4 a0 = *(const float4*)&At[lr * 64 + q * 16 + 0];
        float4 a1 = *(const float4*)&At[lr * 64 + q * 16 + 4];
        float4 a2 = *(const float4*)&At[lr * 64 + q * 16 + 8];
        float4 a3 = *(const float4*)&At[lr * 64 + q * 16 + 12];
        int k0 = q * 16;
        acc0 = fmaf(a0.x, w[k0 + 0],  acc0);
        acc1 = fmaf(a0.y, w[k0 + 1],  acc1);
        acc2 = fmaf(a0.z, w[k0 + 2],  acc2);
        acc3 = fmaf(a0.w, w[k0 + 3],  acc3);
        acc0 = fmaf(a1.x, w[k0 + 4],  acc0);
        acc1 = fmaf(a1.y, w[k0 + 5],  acc1);
        acc2 = fmaf(a1.z, w[k0 + 6],  acc2);
        acc3 = fmaf(a1.w, w[k0 + 7],  acc3);
        acc0 = fmaf(a2.x, w[k0 + 8],  acc0);
        acc1 = fmaf(a2.y, w[k0 + 9],  acc1);
        acc2 = fmaf(a2.z, w[k0 + 10], acc2);
        acc3 = fmaf(a2.w, w[k0 + 11], acc3);
        acc0 = fmaf(a3.x, w[k0 + 12], acc0);
        acc1 = fmaf(a3.y, w[k0 + 13], acc1);
        acc2 = fmaf(a3.z, w[k0 + 14], acc2);
        acc3 = fmaf(a3.w, w[k0 + 15], acc3);
      }
      if (r < n)
        C[(size_t)r * 64 + lane] = ((acc0 + acc1) + (acc2 + acc3)) * dinv[r];
    }
    __syncthreads();
  }
}

// ---- gather aggregation: wave per node, 4 edges x float4 lanes -----------
// hs = row-scaled features (hs[r] = h[r]*dinv[r]).
// out[i][:] = relu( dinv[i] * (sum_edges hs[src] + hs[i]) + b )
template <int RELU>
__global__ __launch_bounds__(THREADS) void k_agg64(
    const float* __restrict__ hs, const float* __restrict__ dinv,
    const int* __restrict__ rowptr, const int* __restrict__ es,
    const float* __restrict__ b, float* __restrict__ out, int n) {
  int i = (blockIdx.x * THREADS + threadIdx.x) >> 6;
  if (i >= n) return;
  int lane = threadIdx.x & 63;
  int g = lane >> 4;        // edge slot 0..3
  int c = lane & 15;        // float4 column group
  const float4* h4 = (const float4*)hs;
  int p1 = rowptr[i + 1];
  int p = rowptr[i] + g;
  float4 acc  = make_float4(0.f, 0.f, 0.f, 0.f);
  float4 acc2 = make_float4(0.f, 0.f, 0.f, 0.f);
  for (; p + 4 < p1; p += 8) {
    int s0 = es[p];
    int s1 = es[p + 4];
    float4 a0 = h4[(size_t)s0 * 16 + c];
    float4 a1 = h4[(size_t)s1 * 16 + c];
    acc.x  += a0.x; acc.y  += a0.y; acc.z  += a0.z; acc.w  += a0.w;
    acc2.x += a1.x; acc2.y += a1.y; acc2.z += a1.z; acc2.w += a1.w;
  }
  if (p < p1) {
    int s0 = es[p];
    float4 a0 = h4[(size_t)s0 * 16 + c];
    acc.x += a0.x; acc.y += a0.y; acc.z += a0.z; acc.w += a0.w;
  }
  acc.x += acc2.x; acc.y += acc2.y; acc.z += acc2.z; acc.w += acc2.w;
#pragma unroll
  for (int m = 16; m <= 32; m <<= 1) {
    acc.x += __shfl_xor(acc.x, m, 64);
    acc.y += __shfl_xor(acc.y, m, 64);
    acc.z += __shfl_xor(acc.z, m, 64);
    acc.w += __shfl_xor(acc.w, m, 64);
  }
  if (g == 0) {
    float di = dinv[i];
    float4 self = h4[(size_t)i * 16 + c];
    float4 bb = ((const float4*)b)[c];
    float4 r;
    r.x = di * (acc.x + self.x) + bb.x;
    r.y = di * (acc.y + self.y) + bb.y;
    r.z = di * (acc.z + self.z) + bb.z;
    r.w = di * (acc.w + self.w) + bb.w;
    if (RELU) {
      r.x = fmaxf(r.x, 0.f); r.y = fmaxf(r.y, 0.f);
      r.z = fmaxf(r.z, 0.f); r.w = fmaxf(r.w, 0.f);
    }
    ((float4*)out)[(size_t)i * 16 + c] = r;
  }
}

// ---- layer 3: g3[i] = (a2[i,:] @ W3) * dinv[i] ---------------------------
__global__ __launch_bounds__(THREADS) void k_gemv(
    const float* __restrict__ a2, const float* __restrict__ W3,
    const float* __restrict__ dinv, float* __restrict__ g3, int n) {
  int t = blockIdx.x * blockDim.x + threadIdx.x;
  int i = t >> 4, p = t & 15;
  if (i >= n) return;
  float4 v = ((const float4*)a2)[t];
  float4 w = ((const float4*)W3)[p];
  float sum = v.x * w.x + v.y * w.y + v.z * w.z + v.w * w.w;
  sum += __shfl_down(sum, 8, 16);
  sum += __shfl_down(sum, 4, 16);
  sum += __shfl_down(sum, 2, 16);
  sum += __shfl_down(sum, 1, 16);
  if (p == 0) g3[i] = sum * dinv[i];
}

// ---- layer-3 aggregation: thread per node --------------------------------
__global__ __launch_bounds__(THREADS) void k_agg1(
    const float* __restrict__ g3, const float* __restrict__ dinv,
    const int* __restrict__ rowptr, const int* __restrict__ es,
    const float* __restrict__ b3, float* __restrict__ out, int n) {
  int i = blockIdx.x * blockDim.x + threadIdx.x;
  if (i >= n) return;
  int p = rowptr[i], p1 = rowptr[i + 1];
  float acc = 0.f, accb = 0.f;
  for (; p + 1 < p1; p += 2) {
    acc  += g3[es[p]];
    accb += g3[es[p + 1]];
  }
  if (p < p1) acc += g3[es[p]];
  out[i] = dinv[i] * (acc + accb + g3[i]) + b3[0];
}

extern "C" void kernel_launch(void* const* d_in, const int* in_sizes, int n_in,
                              void* d_out, int out_size, void* d_ws, size_t ws_size,
                              hipStream_t stream) {
  const float* x  = (const float*)d_in[0];
  const int*   ei = (const int*)d_in[1];
  const float* W1 = (const float*)d_in[2];
  const float* b1 = (const float*)d_in[3];
  const float* W2 = (const float*)d_in[4];
  const float* b2 = (const float*)d_in[5];
  const float* W3 = (const float*)d_in[6];
  const float* b3 = (const float*)d_in[7];
  float* out = (float*)d_out;

  const int n = in_sizes[0] / 64;    // 100000
  const int E = in_sizes[1] / 2;     // 1600000
  const int* src = ei;
  const int* dst = ei + E;
  const int nbuck = (n + NPB - 1) >> NPB_SHIFT;       // 196
  const int nA = (E + 4095) / 4096;                   // blocks for hist/scat

  // workspace layout, 256B-aligned regions
  char* w = (char*)d_ws;
  auto alloc = [&](size_t bytes) -> void* {
    void* p = (void*)w;
    w += (bytes + 255) & ~(size_t)255;
    return p;
  };
  int*   bucketCnt = (int*)alloc(256 * 4);
  int*   bucketOff = (int*)alloc(257 * 4);
  int*   bucketCur = (int*)alloc(256 * 4);
  int*   rowptr    = (int*)alloc(((size_t)n + 1) * 4);
  int*   eb        = (int*)alloc((size_t)E * 4);
  int*   es        = (int*)alloc((size_t)E * 4);
  float* dinv      = (float*)alloc((size_t)n * 4);
  float* g3        = (float*)alloc((size_t)n * 4);
  float* bufA      = (float*)alloc((size_t)n * 64 * 4);
  float* bufB      = (float*)alloc((size_t)n * 64 * 4);

  const int gN    = (n + THREADS - 1) / THREADS;
  const int gN16  = ((n * 16) + THREADS - 1) / THREADS;
  const int gGemm = 1024;              // grid-stride over 6250 tiles
  const int gWave = (n + 3) / 4;

  // bucketed CSR build
  hipMemsetAsync(bucketCnt, 0, 256 * 4, stream);
  k_bhist<<<nA, THREADS, 0, stream>>>(dst, bucketCnt, E);
  k_bscan<<<1, THREADS, 0, stream>>>(bucketCnt, bucketOff, bucketCur, rowptr, n, E, nbuck);
  k_bscat<<<nA, THREADS, 0, stream>>>(src, dst, bucketCur, eb, E);
  k_bcsr<<<nbuck, THREADS, 0, stream>>>(eb, bucketOff, rowptr, dinv, es, n);

  // layer 1: hs1 = (x@W1)*dinv -> bufA; a1 = agg(hs1) -> bufB
  k_gemmT<<<gGemm, THREADS, 0, stream>>>(x, W1, dinv, bufA, n);
  k_agg64<1><<<gWave, THREADS, 0, stream>>>(bufA, dinv, rowptr, es, b1, bufB, n);
  // layer 2: hs2 = (a1@W2)*dinv -> bufA; a2 = agg(hs2) -> bufB
  k_gemmT<<<gGemm, THREADS, 0, stream>>>(bufB, W2, dinv, bufA, n);
  k_agg64<1><<<gWave, THREADS, 0, stream>>>(bufA, dinv, rowptr, es, b2, bufB, n);
  // layer 3: g3 = (a2@W3)*dinv; out = dinv*(agg(g3)+g3) + b3
  k_gemv<<<gN16, THREADS, 0, stream>>>(bufB, W3, dinv, g3, n);
  k_agg1<<<gN, THREADS, 0, stream>>>(g3, dinv, rowptr, es, b3, out, n);
}